// Round 5
// baseline (350.445 us; speedup 1.0000x reference)
//
#include <hip/hip_runtime.h>

#define DMODEL    2048
#define F4ROW     (DMODEL / 4)          // 512 float4 per row
#define ROWSHIFT  9                     // g >> 9 = row
#define NTHREADS  256
#define WPB       (NTHREADS / 64)       // waves per block
#define MAXBLK    2048                  // G11: cap grid, grid-stride the rest
#define MAXROWS_STATIC 16384

typedef float fx4 __attribute__((ext_vector_type(4)));

// Row-sum scratch: static device buffer (B=8192 per problem; 16384 for slack).
// Avoids d_ws entirely (round-4 container crash suspect: unverified ws_size).
__device__ float g_rowsum[MAXROWS_STATIC];

// sin/cos of theta (radians) via hardware v_sin_f32/v_cos_f32.
// HW takes REVOLUTIONS; fract-reduce first (exact: periodic in 1 rev).
// Matches the reference's 4096-entry lerp LUT to ~3e-7; threshold is 2e-2.
__device__ __forceinline__ void fast_sincos(float theta, float& s, float& c) {
    const float INV_TWO_PI = 0.15915494309189535f;
    float r  = theta * INV_TWO_PI;
    float rr = r - floorf(r);                 // [0,1) revolutions
#if __has_builtin(__builtin_amdgcn_sinf) && __has_builtin(__builtin_amdgcn_cosf)
    s = __builtin_amdgcn_sinf(rr);
    c = __builtin_amdgcn_cosf(rr);
#else
    s = __sinf(rr * 6.283185307179586f);
    c = __cosf(rr * 6.283185307179586f);
#endif
}

__device__ __forceinline__ float fast_rcp(float x) {
#if __has_builtin(__builtin_amdgcn_rcpf)
    return __builtin_amdgcn_rcpf(x);          // ~1e-7 rel err, plenty for 2e-2
#else
    return 1.0f / x;
#endif
}

template <typename T>
__device__ __forceinline__ void nt_store(T v, T* p) {
#if __has_builtin(__builtin_nontemporal_store)
    __builtin_nontemporal_store(v, p);        // write-only output: don't cache
#else
    *p = v;
#endif
}

// ======================= Kernel 1: interference sums =======================
// Row-per-wave: lane l sums chunks {l + 64k}, k=0..7; shuffle-reduce; lane 0
// does ONE plain store (no atomics -> no zeroing -> no memset).
// No LDS, no barriers; 8 independent unrolled iterations give the scheduler
// a continuous load stream. 8192 waves = 32/CU.
__global__ __launch_bounds__(NTHREADS)
void k1_interference(const float* __restrict__ x_real,
                     const float* __restrict__ x_imag,
                     const float* __restrict__ tvec,
                     const float* __restrict__ w_trigger,
                     const float* __restrict__ b_trigger,
                     float* __restrict__ rowsum_ext,
                     int use_ext,
                     int nrows)
{
    const int lane = threadIdx.x & 63;
    const int row  = blockIdx.x * WPB + (threadIdx.x >> 6);
    if (row >= nrows) return;

    float* __restrict__ rowsum = use_ext ? rowsum_ext : g_rowsum;

    const float t_phi = tvec[row] * 1.6180339887498948f;   // PHI
    const fx4* Xr = (const fx4*)x_real + (size_t)row * F4ROW;
    const fx4* Xi = (const fx4*)x_imag + (size_t)row * F4ROW;
    const fx4* Wt = (const fx4*)w_trigger;                 // L2-hot broadcast
    const fx4* Bt = (const fx4*)b_trigger;

    float p = 0.0f;
    #pragma unroll
    for (int k = 0; k < 8; ++k) {
        const int c = k * 64 + lane;                       // coalesced 1KB/wave
        const fx4 xr = Xr[c];
        const fx4 xi = Xi[c];
        const fx4 wt = Wt[c];
        const fx4 bt = Bt[c];
        #pragma unroll
        for (int j = 0; j < 4; ++j) {
            // trigger = cis(th_r + th_i); contribution = cos*xr + sin*xi
            float iw   = fast_rcp(1.0f + fabsf(wt[j]));
            float base = bt[j] + t_phi;
            float s, cc;
            fast_sincos(fmaf(xr[j] + xi[j], iw, base + base), s, cc);
            p = fmaf(cc, xr[j], p);
            p = fmaf(s,  xi[j], p);
        }
    }
    #pragma unroll
    for (int off = 32; off > 0; off >>= 1)
        p += __shfl_xor(p, off, 64);
    if (lane == 0) rowsum[row] = p;                        // plain store
}

// ======================= Kernel 2: blend + evolve ==========================
// Pure streaming: grid-stride, explicit 2-deep A/B pipeline (named stages, no
// runtime-indexed arrays); reads x(+L3), memory, L2-hot params/rowsum;
// nt-stores output. No LDS, no barriers, no cross-thread deps.

struct S2 { fx4 xr, xi, mr, mi, ws, bs; float tphi, sum; };

__device__ __forceinline__ void load2(S2& S, int g,
        const float* __restrict__ xr, const float* __restrict__ xi,
        const float* __restrict__ mr, const float* __restrict__ mi,
        const float* __restrict__ tv, const float* __restrict__ rowsum,
        const float* __restrict__ ws, const float* __restrict__ bs) {
    S.xr = ((const fx4*)xr)[g];                       // HBM/L3 stream
    S.xi = ((const fx4*)xi)[g];
    S.mr = ((const fx4*)mr)[g];                       // HBM stream
    S.mi = ((const fx4*)mi)[g];
    const int c = g & (F4ROW - 1);
    S.ws = ((const fx4*)ws)[c];                       // L2-hot broadcast
    S.bs = ((const fx4*)bs)[c];
    const int row = g >> ROWSHIFT;
    S.tphi = tv[row] * 1.6180339887498948f;           // PHI; L2-hot
    S.sum  = rowsum[row];                             // L2-hot (32 KB)
}

__device__ __forceinline__ void compute2(const S2& S, int g, float k_eff,
                                         float* __restrict__ outr,
                                         float* __restrict__ outi) {
    float ic    = S.sum * (1.0f / 45.254833995939045f);   // / sqrt(2048)
    ic          = fminf(1.0f, fmaxf(-1.0f, ic));
    float x_inv = (1.0f - ic) * 0.5f;
    const float alpha = __expf(-k_eff * x_inv);
    const float oma   = 1.0f - alpha;
    fx4 er, ei;
    #pragma unroll
    for (int j = 0; j < 4; ++j) {
        // (br+bi) = alpha*(xr+xi) + oma*(mr+mi); evolved = cis(th_sr+th_si)
        float sb   = fmaf(alpha, S.xr[j] + S.xi[j], oma * (S.mr[j] + S.mi[j]));
        float iw   = fast_rcp(1.0f + fabsf(S.ws[j]));
        float base = S.bs[j] + S.tphi;
        float s, c;
        fast_sincos(fmaf(sb, iw, base + base), s, c);
        er[j] = c;
        ei[j] = s;
    }
    nt_store(er, (fx4*)outr + g);
    nt_store(ei, (fx4*)outi + g);
}

__global__ __launch_bounds__(NTHREADS)
void k2_evolve(const float* __restrict__ x_real,
               const float* __restrict__ x_imag,
               const float* __restrict__ tvec,
               const float* __restrict__ memory_real,
               const float* __restrict__ memory_imag,
               const float* __restrict__ w_state,
               const float* __restrict__ b_state,
               const float* __restrict__ kptr,
               const float* __restrict__ rowsum_ext,
               int use_ext,
               float* __restrict__ out,
               int n_f4,
               size_t imag_off)
{
    const float* __restrict__ rowsum = use_ext ? rowsum_ext : g_rowsum;
    const float k_eff = fabsf(kptr[0]) + 0.1f;
    float* outr = out;
    float* outi = out + imag_off;

    const int stride = gridDim.x * blockDim.x;
    int g = blockIdx.x * blockDim.x + threadIdx.x;
    if (g >= n_f4) return;

    S2 A, B;
    load2(A, g, x_real, x_imag, memory_real, memory_imag,
          tvec, rowsum, w_state, b_state);
    int gn = g + stride;
    while (gn < n_f4) {
        load2(B, gn, x_real, x_imag, memory_real, memory_imag,
              tvec, rowsum, w_state, b_state);
        compute2(A, g, k_eff, outr, outi);            // B stays in flight
        g = gn; gn += stride;
        if (gn < n_f4) {
            load2(A, gn, x_real, x_imag, memory_real, memory_imag,
                  tvec, rowsum, w_state, b_state);
            compute2(B, g, k_eff, outr, outi);        // A stays in flight
            g = gn; gn += stride;
        } else {
            compute2(B, g, k_eff, outr, outi);
            return;
        }
    }
    compute2(A, g, k_eff, outr, outi);
}

extern "C" void kernel_launch(void* const* d_in, const int* in_sizes, int n_in,
                              void* d_out, int out_size, void* d_ws, size_t ws_size,
                              hipStream_t stream) {
    const float* x_real      = (const float*)d_in[0];
    const float* x_imag      = (const float*)d_in[1];
    const float* t           = (const float*)d_in[2];
    const float* memory_real = (const float*)d_in[3];
    const float* memory_imag = (const float*)d_in[4];
    const float* w_trigger   = (const float*)d_in[5];
    const float* b_trigger   = (const float*)d_in[6];
    const float* w_state     = (const float*)d_in[7];
    const float* b_state     = (const float*)d_in[8];
    const float* k           = (const float*)d_in[9];
    // d_in[10], d_in[11] = sin/cos tables — superseded by HW trig
    float* out = (float*)d_out;

    const int B    = in_sizes[0] / DMODEL;
    const int n_f4 = B * F4ROW;
    const size_t imag_off = (size_t)out_size / 2;     // out_size in elements

    // Static device buffer for B<=16384 (the actual case); d_ws only as a
    // guarded fallback for oversized B.
    const int use_ext = (B > MAXROWS_STATIC &&
                         ws_size >= (size_t)B * sizeof(float)) ? 1 : 0;
    float* rowsum_ext = (float*)d_ws;

    int grid1 = (B + WPB - 1) / WPB;
    int grid2 = (n_f4 + NTHREADS - 1) / NTHREADS;
    if (grid2 > MAXBLK) grid2 = MAXBLK;

    k1_interference<<<grid1, NTHREADS, 0, stream>>>(
        x_real, x_imag, t, w_trigger, b_trigger, rowsum_ext, use_ext, B);

    k2_evolve<<<grid2, NTHREADS, 0, stream>>>(
        x_real, x_imag, t, memory_real, memory_imag,
        w_state, b_state, k, rowsum_ext, use_ext, out, n_f4, imag_off);
}

// Round 6
// 344.785 us; speedup vs baseline: 1.0164x; 1.0164x over previous
//
#include <hip/hip_runtime.h>

#define DMODEL   2048
#define F4ROW    (DMODEL / 4)       // 512 fx4 per row
#define NTHREADS 256
#define WPB      (NTHREADS / 64)    // 4 rows per block (one row per wave)
#define CPL      8                  // fx4 chunks per lane (512/64)

typedef float fx4 __attribute__((ext_vector_type(4)));

// sin/cos of theta (radians) via hardware v_sin_f32/v_cos_f32.
// HW takes REVOLUTIONS; fract-reduce first (exact: periodic in 1 rev).
// Matches the reference's 4096-entry lerp LUT to ~3e-7; threshold is 2e-2.
__device__ __forceinline__ void fast_sincos(float theta, float& s, float& c) {
    const float INV_TWO_PI = 0.15915494309189535f;
    float r  = theta * INV_TWO_PI;
    float rr = r - floorf(r);                 // [0,1) revolutions
#if __has_builtin(__builtin_amdgcn_sinf) && __has_builtin(__builtin_amdgcn_cosf)
    s = __builtin_amdgcn_sinf(rr);
    c = __builtin_amdgcn_cosf(rr);
#else
    s = __sinf(rr * 6.283185307179586f);
    c = __cosf(rr * 6.283185307179586f);
#endif
}

__device__ __forceinline__ float fast_rcp(float x) {
#if __has_builtin(__builtin_amdgcn_rcpf)
    return __builtin_amdgcn_rcpf(x);          // ~1e-7 rel err, plenty for 2e-2
#else
    return 1.0f / x;
#endif
}

template <typename T>
__device__ __forceinline__ void nt_store(T v, T* p) {
#if __has_builtin(__builtin_nontemporal_store)
    __builtin_nontemporal_store(v, p);        // write-only output: don't cache
#else
    *p = v;
#endif
}

// Fused, minimum-motion, zero-sync kernel.
//  - One row per WAVE: reduction is 6x shfl_xor, wave-local. NO LDS, NO
//    barrier, NO second kernel, NO workspace.
//  - Phase 2 needs only sxy = xr+xi: stashed in 32 constant-indexed VGPRs
//    during phase 1 -> x is read from HBM exactly ONCE (403 MB total motion,
//    the information-theoretic minimum for this op).
//  - Both phases use k2's (round-5) proven streaming shape: explicit 2-deep
//    A/B chunk pipeline, 4 loads per stage -- the compiler handled this
//    pattern well (VGPR 36, 5.0 TB/s effective motion).
__global__ __launch_bounds__(NTHREADS)
void liquid_echo_fused(const float* __restrict__ x_real,
                       const float* __restrict__ x_imag,
                       const float* __restrict__ tvec,
                       const float* __restrict__ memory_real,
                       const float* __restrict__ memory_imag,
                       const float* __restrict__ w_trigger,
                       const float* __restrict__ b_trigger,
                       const float* __restrict__ w_state,
                       const float* __restrict__ b_state,
                       const float* __restrict__ kptr,
                       float* __restrict__ out,
                       int nrows,
                       size_t imag_off)
{
    const int lane = threadIdx.x & 63;
    const int row  = blockIdx.x * WPB + (threadIdx.x >> 6);
    if (row >= nrows) return;                 // no barriers -> safe

    const float t_phi = tvec[row] * 1.6180339887498948f;   // PHI
    const float k_eff = fabsf(kptr[0]) + 0.1f;             // L2-hot scalar

    const size_t rb4 = (size_t)row * F4ROW;
    const fx4* Xr = (const fx4*)x_real + rb4;
    const fx4* Xi = (const fx4*)x_imag + rb4;
    const fx4* Mr = (const fx4*)memory_real + rb4;
    const fx4* Mi = (const fx4*)memory_imag + rb4;
    const fx4* Wt = (const fx4*)w_trigger;    // L2-hot broadcasts
    const fx4* Bt = (const fx4*)b_trigger;
    const fx4* Ws = (const fx4*)w_state;
    const fx4* Bs = (const fx4*)b_state;

    float sxy[4 * CPL];                       // 32 floats, constant-indexed
    float p = 0.0f;

    // ---- Phase 1: trigger dot-product, streaming A/B pipeline over chunks
    //   trigger = cis(th_r + th_i); contribution = cos*xr + sin*xi
    fx4 xrA = Xr[lane], xiA = Xi[lane];
    fx4 wtA = Wt[lane], btA = Bt[lane];
    #pragma unroll
    for (int k = 0; k < CPL; k += 2) {
        const int cB = (k + 1) * 64 + lane;   // compile-time k -> const idx
        fx4 xrB = Xr[cB], xiB = Xi[cB];
        fx4 wtB = Wt[cB], btB = Bt[cB];
        #pragma unroll
        for (int j = 0; j < 4; ++j) {
            float sx = xrA[j] + xiA[j];
            sxy[k * 4 + j] = sx;
            float iw   = fast_rcp(1.0f + fabsf(wtA[j]));
            float base = btA[j] + t_phi;
            float s, c;
            fast_sincos(fmaf(sx, iw, base + base), s, c);
            p = fmaf(c, xrA[j], p);
            p = fmaf(s, xiA[j], p);
        }
        if (k + 2 < CPL) {
            const int cA = (k + 2) * 64 + lane;
            xrA = Xr[cA]; xiA = Xi[cA]; wtA = Wt[cA]; btA = Bt[cA];
        }
        #pragma unroll
        for (int j = 0; j < 4; ++j) {
            float sx = xrB[j] + xiB[j];
            sxy[(k + 1) * 4 + j] = sx;
            float iw   = fast_rcp(1.0f + fabsf(wtB[j]));
            float base = btB[j] + t_phi;
            float s, c;
            fast_sincos(fmaf(sx, iw, base + base), s, c);
            p = fmaf(c, xrB[j], p);
            p = fmaf(s, xiB[j], p);
        }
    }

    // ---- Prefetch phase-2 chunk 0 BEFORE the reduce (hides HBM latency
    //      under the shuffle chain + exp; no barrier exists to drain it)
    fx4 mrA = Mr[lane], miA = Mi[lane];
    fx4 wsA = Ws[lane], bsA = Bs[lane];

    // ---- Wave-local reduction: the row is wave-owned
    #pragma unroll
    for (int off = 32; off > 0; off >>= 1)
        p += __shfl_xor(p, off, 64);

    float ic = p * (1.0f / 45.254833995939045f);           // / sqrt(2048)
    ic       = fminf(1.0f, fmaxf(-1.0f, ic));
    const float alpha = __expf(-k_eff * (1.0f - ic) * 0.5f);
    const float oma   = 1.0f - alpha;

    fx4* Or = (fx4*)out + rb4;
    fx4* Oi = (fx4*)(out + imag_off) + rb4;

    // ---- Phase 2: blend + evolve, same streaming pipeline; sxy from regs
    //   (br+bi) = alpha*sxy + oma*(mr+mi); evolved = cis(th_sr + th_si)
    #pragma unroll
    for (int k = 0; k < CPL; k += 2) {
        const int cB = (k + 1) * 64 + lane;
        fx4 mrB = Mr[cB], miB = Mi[cB];
        fx4 wsB = Ws[cB], bsB = Bs[cB];
        fx4 er, ei;
        #pragma unroll
        for (int j = 0; j < 4; ++j) {
            float sb   = fmaf(alpha, sxy[k * 4 + j], oma * (mrA[j] + miA[j]));
            float iw   = fast_rcp(1.0f + fabsf(wsA[j]));
            float base = bsA[j] + t_phi;
            float s, c;
            fast_sincos(fmaf(sb, iw, base + base), s, c);
            er[j] = c;
            ei[j] = s;
        }
        nt_store(er, Or + (k * 64 + lane));
        nt_store(ei, Oi + (k * 64 + lane));
        if (k + 2 < CPL) {
            const int cA = (k + 2) * 64 + lane;
            mrA = Mr[cA]; miA = Mi[cA]; wsA = Ws[cA]; bsA = Bs[cA];
        }
        #pragma unroll
        for (int j = 0; j < 4; ++j) {
            float sb   = fmaf(alpha, sxy[(k + 1) * 4 + j], oma * (mrB[j] + miB[j]));
            float iw   = fast_rcp(1.0f + fabsf(wsB[j]));
            float base = bsB[j] + t_phi;
            float s, c;
            fast_sincos(fmaf(sb, iw, base + base), s, c);
            er[j] = c;
            ei[j] = s;
        }
        nt_store(er, Or + cB);
        nt_store(ei, Oi + cB);
    }
}

extern "C" void kernel_launch(void* const* d_in, const int* in_sizes, int n_in,
                              void* d_out, int out_size, void* d_ws, size_t ws_size,
                              hipStream_t stream) {
    const float* x_real      = (const float*)d_in[0];
    const float* x_imag      = (const float*)d_in[1];
    const float* t           = (const float*)d_in[2];
    const float* memory_real = (const float*)d_in[3];
    const float* memory_imag = (const float*)d_in[4];
    const float* w_trigger   = (const float*)d_in[5];
    const float* b_trigger   = (const float*)d_in[6];
    const float* w_state     = (const float*)d_in[7];
    const float* b_state     = (const float*)d_in[8];
    const float* k           = (const float*)d_in[9];
    // d_in[10], d_in[11] = sin/cos tables — superseded by HW trig
    float* out = (float*)d_out;

    const int B = in_sizes[0] / DMODEL;
    const size_t imag_off = (size_t)out_size / 2;

    const int grid = (B + WPB - 1) / WPB;

    liquid_echo_fused<<<grid, NTHREADS, 0, stream>>>(
        x_real, x_imag, t, memory_real, memory_imag,
        w_trigger, b_trigger, w_state, b_state, k,
        out, B, imag_off);
}